// Round 7
// baseline (312.481 us; speedup 1.0000x reference)
//
#include <hip/hip_runtime.h>
#include <stdint.h>

#define TT 8192          // sequence length T
#define BT 16384         // B*T tokens
#define MCH 8192         // token chunk for qkv GEMM + attention

typedef __attribute__((ext_vector_type(8))) __bf16 bf16x8;
typedef __attribute__((ext_vector_type(4))) __bf16 bf16x4;
typedef __attribute__((ext_vector_type(4))) short short4v;
typedef __attribute__((ext_vector_type(4))) float floatx4;

__device__ __forceinline__ float bf2f(unsigned short h) {
  union { unsigned u; float f; } x; x.u = ((unsigned)h) << 16; return x.f;
}
__device__ __forceinline__ unsigned short f2bf(float f) {
  union { float f; unsigned u; } x; x.f = f;
  unsigned r = (x.u + 0x7fffu + ((x.u >> 16) & 1u)) >> 16;
  return (unsigned short)r;
}
__device__ __forceinline__ void async16(const void* g, void* l) {
  __builtin_amdgcn_global_load_lds(
      (__attribute__((address_space(1))) void*)g,
      (__attribute__((address_space(3))) void*)l, 16, 0, 0);
}

// ---------------------------------------------------------------------------
// fp32 -> bf16 conversion (round-to-nearest-even), float4 vectorized.
// ---------------------------------------------------------------------------
__global__ __launch_bounds__(256) void cvt_f2b(
    const float* __restrict__ src, unsigned short* __restrict__ dst, int n4) {
  const int i = blockIdx.x * 256 + threadIdx.x;
  if (i < n4) {
    const float4 f = ((const float4*)src)[i];
    union { uint2 u2; unsigned short s[4]; } o;
    o.s[0] = f2bf(f.x); o.s[1] = f2bf(f.y);
    o.s[2] = f2bf(f.z); o.s[3] = f2bf(f.w);
    ((uint2*)dst)[i] = o.u2;
  }
}

// ---------------------------------------------------------------------------
// Merged prep: RoPE table + Wqkv cvt + Wout cvt in one dispatch.
// blocks [0,1024): tab[t*32+p] = (cos,sin) of t * 10000^(-p/32)
// blocks [1024,4096): Wqkv fp32->bf16 (786432 float4s)
// blocks [4096,5120): Wout fp32->bf16 (262144 float4s)
// ---------------------------------------------------------------------------
__global__ __launch_bounds__(256) void prep_k(
    const float* __restrict__ Wqkv, const float* __restrict__ Wout,
    unsigned short* __restrict__ Wqkvb, unsigned short* __restrict__ Woutb,
    float2* __restrict__ tab) {
  const int bx = blockIdx.x;
  const int tid = threadIdx.x;
  if (bx < 1024) {
    const int i = bx * 256 + tid;
    const int t = i >> 5, p = i & 31;
    const float f = (float)t * exp2f((float)p * -0.41524101186092f); // -log2(1e4)/32
    float s, c;
    sincosf(f, &s, &c);
    tab[i] = make_float2(c, s);
  } else {
    const float* src;
    unsigned short* dst;
    int i;
    if (bx < 4096) { src = Wqkv; dst = Wqkvb; i = (bx - 1024) * 256 + tid; }
    else           { src = Wout; dst = Woutb; i = (bx - 4096) * 256 + tid; }
    const float4 f = ((const float4*)src)[i];
    union { uint2 u2; unsigned short s[4]; } o;
    o.s[0] = f2bf(f.x); o.s[1] = f2bf(f.y);
    o.s[2] = f2bf(f.z); o.s[3] = f2bf(f.w);
    ((uint2*)dst)[i] = o.u2;
  }
}

// ---------------------------------------------------------------------------
// GEMM, occupancy-first pipelined schedule (round-2 exact — best measured):
// C[M,N] = A[M,K] . W[N,K]^T
// BM=256, BN=128, BK=32, 8 waves (4M x 2N), wave-tile 64x64 (acc[4][4]),
// LDS 48 KiB double-buffered, __launch_bounds__(512,4) capping regs so
// 2 blocks/CU (16 waves) fit. One phase per K-tile:
// {8x ds_read_b128 -> barrier -> lgkmcnt(0) -> stage(t+2, 3x gload_lds)
//  -> setprio(1) 16x MFMA setprio(0) -> vmcnt(3) -> barrier}.
// Counted vmcnt(3) keeps the next tile's loads in flight across barriers.
// XOR swizzle chunk ^= (row>>1)&3 on both stage-source and ds_read addr
// (measured 0 bank conflicts). XCD-aware blockIdx swizzle.
// Requires: M%256==0, N%128==0, K%32==0, K/32>=2, grid%8==0.
// ---------------------------------------------------------------------------
template <bool CF32>
__global__ __launch_bounds__(512, 4) void gemm_k32(
    const unsigned short* __restrict__ A,
    const unsigned short* __restrict__ W,
    void* __restrict__ C,
    int M, int N, int K)
{
  // per buf: A [256][32] (16 KB) + B [128][32] (8 KB) = 24 KB; x2 = 48 KiB
  __shared__ __align__(16) unsigned short sm[2][(256 + 128) * 32];

  const int tid  = threadIdx.x;
  const int lane = tid & 63;
  const int wid  = tid >> 6;
  const int wr   = wid >> 1;          // 0..3 : wave row (M, 64 rows each)
  const int wc   = wid & 1;           // 0..1 : wave col (N, 64 cols each)
  const int lm   = lane & 15;
  const int kg   = lane >> 4;
  const int cxor = (lm >> 1) & 3;     // read-side swizzle term ((row>>1)&3)

  // XCD-aware swizzle (grid % 8 == 0 for both call sites -> bijective)
  const int nb  = N >> 7;
  const int cpx = (int)gridDim.x >> 3;
  const int bid = blockIdx.x;
  const int swz = (bid & 7) * cpx + (bid >> 3);
  const int bm  = swz / nb;
  const int bn  = swz % nb;

  const int NT = K >> 5;              // K-tiles of 32

  // ---- staging geometry: 3 x global_load_lds(16B) per wave per tile ----
  const int sr  = lane >> 2;
  const int scb = lane & 3;
  const unsigned short* gsrc0;
  const unsigned short* gsrc1;
  const unsigned short* gsrc2;
  {
    const int r0 = wid * 16 + sr;          // 0..127
    const int r1 = 128 + r0;               // 128..255
    const int rB = wid * 16 + sr;          // 0..127
    gsrc0 = A + (size_t)(bm * 256 + r0) * (size_t)K + ((scb ^ ((r0 >> 1) & 3)) << 3);
    gsrc1 = A + (size_t)(bm * 256 + r1) * (size_t)K + ((scb ^ ((r1 >> 1) & 3)) << 3);
    gsrc2 = W + (size_t)(bn * 128 + rB) * (size_t)K + ((scb ^ ((rB >> 1) & 3)) << 3);
  }
  const int ld0 = wid * 1024;              // A half 0
  const int ld1 = 8192 + wid * 1024;       // A half 1
  const int ld2 = 16384 + wid * 1024;      // B

  auto stage_tile = [&](int tt) {
    char* lb = (char*)sm[tt & 1];
    const size_t koff = (size_t)tt << 5;   // element offset along K
    async16(gsrc0 + koff, lb + ld0);
    async16(gsrc1 + koff, lb + ld1);
    async16(gsrc2 + koff, lb + ld2);
  };

  floatx4 acc[4][4];
  floatx4 z = {0.f, 0.f, 0.f, 0.f};
#pragma unroll
  for (int i = 0; i < 4; ++i)
#pragma unroll
    for (int j = 0; j < 4; ++j) acc[i][j] = z;

  // ---- prologue: tiles 0 and 1 in flight; gate on tile-0 residency ----
  stage_tile(0);
  stage_tile(1);
  asm volatile("s_waitcnt vmcnt(3)" ::: "memory");
  __builtin_amdgcn_s_barrier();
  __builtin_amdgcn_sched_barrier(0);

  for (int t = 0; t < NT; ++t) {
    const unsigned short* Ab = sm[t & 1];
    const unsigned short* Bb = Ab + 256 * 32;

    bf16x8 af[4], bfr[4];
#pragma unroll
    for (int i = 0; i < 4; ++i) {
      const int rr = wr * 64 + i * 16 + lm;
      af[i] = *(const bf16x8*)(Ab + rr * 32 + ((kg ^ cxor) << 3));
    }
#pragma unroll
    for (int j = 0; j < 4; ++j) {
      const int rr = wc * 64 + j * 16 + lm;
      bfr[j] = *(const bf16x8*)(Bb + rr * 32 + ((kg ^ cxor) << 3));
    }

    // all waves' reads of this tile issued before anyone overwrites the buf
    __builtin_amdgcn_s_barrier();
    asm volatile("s_waitcnt lgkmcnt(0)" ::: "memory");
    __builtin_amdgcn_sched_barrier(0);

    if (t + 2 < NT) stage_tile(t + 2);   // overwrites buf just consumed

    __builtin_amdgcn_s_setprio(1);
#pragma unroll
    for (int i = 0; i < 4; ++i)
#pragma unroll
      for (int j = 0; j < 4; ++j)
        acc[i][j] = __builtin_amdgcn_mfma_f32_16x16x32_bf16(
            af[i], bfr[j], acc[i][j], 0, 0, 0);
    __builtin_amdgcn_s_setprio(0);

    if (t + 1 < NT) {
      // gate: tile t+1 resident; tile t+2's 3 loads may stay in flight.
      if (t + 2 < NT)
        asm volatile("s_waitcnt vmcnt(3)" ::: "memory");
      else
        asm volatile("s_waitcnt vmcnt(0)" ::: "memory");
      __builtin_amdgcn_s_barrier();
      __builtin_amdgcn_sched_barrier(0);
    }
  }

  // ---- epilogue ----
#pragma unroll
  for (int i = 0; i < 4; ++i) {
    const int row0 = bm * 256 + wr * 64 + i * 16 + kg * 4;
#pragma unroll
    for (int j = 0; j < 4; ++j) {
      const int col = bn * 128 + wc * 64 + j * 16 + lm;
#pragma unroll
      for (int r = 0; r < 4; ++r) {
        if (CF32)
          ((float*)C)[(size_t)(row0 + r) * N + col] = acc[i][j][r];
        else
          ((unsigned short*)C)[(size_t)(row0 + r) * N + col] = f2bf(acc[i][j][r]);
      }
    }
  }
}

// ---------------------------------------------------------------------------
// MFMA-based per-token head-attention with fused RoPE (table-based).
// Chain-cut rewrite: the Q/K LDS round-trip (write -> lgkm drain -> read)
// is replaced by in-register RoPE + ds_bpermute lane permutation. The MFMA
// fragment is a pure lane permute of the load layout: dst lane (lm,quad),
// half h needs source lane (lm&7)*8 + h*4 + quad's full 16B chunk (chunk 0/1
// for Q, 2/3 for K, chosen by lm<8). Only V goes through LDS ([16][72] bf16,
// 2.3 KB/wave). All 16 scalar V reads hoisted before the 4 PV MFMAs; tab
// loads hoisted to 2/token. 256-thr blocks (4 waves), 2 prefetched tokens
// per wave, __launch_bounds__(256,4) -> 16 waves/CU.
// Scores: S^T = K.Q^T -> s4[r] = S[lm][quad*4+r]. PV via mfma_16x16x16
// (S^T C-layout == P A-layout). Output layout (== reference reshape):
//   Y[b*8192 + qh*512 + t/16][(t&15)*64 + d]
// ---------------------------------------------------------------------------
#if defined(__has_builtin)
#if __has_builtin(__builtin_amdgcn_mfma_f32_16x16x16_bf16)
#define PV_MFMA 1
#define PV_MFMA_CALL(a, b, c) __builtin_amdgcn_mfma_f32_16x16x16_bf16( \
    *(bf16x4*)&(a), *(bf16x4*)&(b), (c), 0, 0, 0)
#elif __has_builtin(__builtin_amdgcn_mfma_f32_16x16x16bf16_1k)
#define PV_MFMA 1
#define PV_MFMA_CALL(a, b, c) __builtin_amdgcn_mfma_f32_16x16x16bf16_1k( \
    (a), (b), (c), 0, 0, 0)
#else
#define PV_MFMA 0
#endif
#else
#define PV_MFMA 0
#endif

__global__ __launch_bounds__(256, 4) void attn_rope_k(
    const unsigned short* __restrict__ qkv,   // chunk-local, MCH tokens
    const float2* __restrict__ tab,
    unsigned short* __restrict__ Y,
    int base)
{
  // per-wave V slot only: [16 heads][72] bf16 (pad 8/row, b128-friendly)
  __shared__ __align__(16) unsigned short sV[4][16 * 72];
#if !PV_MFMA
  __shared__ float sP[4][256];
#endif

  const int wave = threadIdx.x >> 6;
  const int lane = threadIdx.x & 63;
  const int lm   = lane & 15;
  const int quad = lane >> 4;
  const int ml0  = blockIdx.x * 8 + wave * 2;   // 2 sequential tokens/wave
  unsigned short* VB = sV[wave];

  const int hlo = lane >> 3;          // head index for even chunks (odd: +8)
  const int d0  = (lane & 7) * 8;     // dim offset of this lane's chunk
  const int p0  = d0 >> 1;            // rope table offset

  // ---- issue both tokens' loads up front (12 qkv b128 + 4 tab f4) ----
  uint4 R[2][6];
  float4 CS[2][2];
  int tA[2], bA[2];
#pragma unroll
  for (int tk = 0; tk < 2; ++tk) {
    const int m = base + ml0 + tk;
    tA[tk] = m & (TT - 1);
    bA[tk] = m >> 13;
    const uint4* row = (const uint4*)(qkv + (size_t)(ml0 + tk) * 3072);
#pragma unroll
    for (int i = 0; i < 6; ++i) R[tk][i] = row[lane + 64 * i];
    CS[tk][0] = *(const float4*)(tab + (tA[tk] << 5) + p0);
    CS[tk][1] = *(const float4*)(tab + (tA[tk] << 5) + p0 + 2);
  }

#pragma unroll
  for (int tk = 0; tk < 2; ++tk) {
    const int t = tA[tk];
    const float cs[4] = {CS[tk][0].x, CS[tk][0].z, CS[tk][1].x, CS[tk][1].z};
    const float sn[4] = {CS[tk][0].y, CS[tk][0].w, CS[tk][1].y, CS[tk][1].w};

    // ---- RoPE in-register on the 4 Q/K chunks ----
    uint4 P[4];
#pragma unroll
    for (int i = 0; i < 4; ++i) {
      union { uint4 u4; unsigned short s[8]; } cv;
      cv.u4 = R[tk][i];
      float f[8];
#pragma unroll
      for (int j = 0; j < 8; ++j) f[j] = bf2f(cv.s[j]);
#pragma unroll
      for (int j = 0; j < 4; ++j) {
        const float x1 = f[2 * j], x2 = f[2 * j + 1];
        cv.s[2 * j]     = f2bf(x1 * cs[j] - x2 * sn[j]);
        cv.s[2 * j + 1] = f2bf(x2 * cs[j] + x1 * sn[j]);
      }
      P[i] = cv.u4;
    }

    // ---- V -> LDS (2 b128 writes; no rope) ----
    *(uint4*)(VB + hlo * 72 + d0)       = R[tk][4];
    *(uint4*)(VB + (8 + hlo) * 72 + d0) = R[tk][5];

    // ---- scores: S^T = K.Q^T; fragments via ds_bpermute lane permute ----
    __builtin_amdgcn_s_setprio(1);
    floatx4 accS = {0.f, 0.f, 0.f, 0.f};
#pragma unroll
    for (int half = 0; half < 2; ++half) {
      const int bpi = (((lm & 7) * 8) + half * 4 + quad) * 4;
      union { int w[4]; bf16x8 v; } kf, qf;
#pragma unroll
      for (int w = 0; w < 4; ++w) {
        const int q0 = __builtin_amdgcn_ds_bpermute(bpi, (int)(&P[0].x)[w]);
        const int q1 = __builtin_amdgcn_ds_bpermute(bpi, (int)(&P[1].x)[w]);
        qf.w[w] = lm < 8 ? q0 : q1;
        const int k0 = __builtin_amdgcn_ds_bpermute(bpi, (int)(&P[2].x)[w]);
        const int k1 = __builtin_amdgcn_ds_bpermute(bpi, (int)(&P[3].x)[w]);
        kf.w[w] = lm < 8 ? k0 : k1;
      }
      accS = __builtin_amdgcn_mfma_f32_16x16x32_bf16(kf.v, qf.v, accS, 0, 0, 0);
    }

    // accS[r] = S[q=lm][k=quad*4+r] ; softmax over 16 k (within lm rows)
    float s4[4];
    float mx = -1e30f;
#pragma unroll
    for (int j = 0; j < 4; ++j) { s4[j] = accS[j] * 0.125f; mx = fmaxf(mx, s4[j]); }
    mx = fmaxf(mx, __shfl_xor(mx, 16, 64));
    mx = fmaxf(mx, __shfl_xor(mx, 32, 64));
    float sum = 0.f;
#pragma unroll
    for (int j = 0; j < 4; ++j) { s4[j] = __expf(s4[j] - mx); sum += s4[j]; }
    sum += __shfl_xor(sum, 16, 64);
    sum += __shfl_xor(sum, 32, 64);
    const float inv = 1.0f / sum;

#if PV_MFMA
    // ---- PV via mfma_16x16x16 (S^T C-layout == P A-layout) ----
    union { short4v v; unsigned short s[4]; } pf;
#pragma unroll
    for (int j = 0; j < 4; ++j) pf.s[j] = f2bf(s4[j] * inv);
    // hoist ALL 16 V reads (independent) ahead of the 4 MFMAs
    unsigned short vs[16];
#pragma unroll
    for (int dtile = 0; dtile < 4; ++dtile)
#pragma unroll
      for (int j = 0; j < 4; ++j)
        vs[dtile * 4 + j] = VB[(quad * 4 + j) * 72 + dtile * 16 + lm];
#pragma unroll
    for (int dtile = 0; dtile < 4; ++dtile) {
      union { short4v v; unsigned short s[4]; } vf;
#pragma unroll
      for (int j = 0; j < 4; ++j) vf.s[j] = vs[dtile * 4 + j];
      floatx4 accO = {0.f, 0.f, 0.f, 0.f};
      accO = PV_MFMA_CALL(pf.v, vf.v, accO);
      const int col = (t & 15) * 64 + dtile * 16 + lm;
#pragma unroll
      for (int r = 0; r < 4; ++r) {
        const size_t rr = (size_t)bA[tk] * TT + (size_t)(quad * 4 + r) * 512 + (t >> 4);
        Y[rr * 1024 + col] = f2bf(accO[r]);
      }
    }
    __builtin_amdgcn_s_setprio(0);
#else
    // ---- VALU fallback: P via per-wave LDS slice (wave-local drains) ----
    __builtin_amdgcn_s_setprio(0);
    float* Pp = sP[wave];
#pragma unroll
    for (int j = 0; j < 4; ++j) Pp[(quad * 4 + j) * 16 + lm] = s4[j] * inv;
    asm volatile("s_waitcnt lgkmcnt(0)" ::: "memory");
    __builtin_amdgcn_sched_barrier(0);
    float o[16];
#pragma unroll
    for (int dd = 0; dd < 16; ++dd) o[dd] = 0.f;
#pragma unroll
    for (int kh = 0; kh < 16; ++kh) {
      const float a = Pp[kh * 16 + lm];
      union { uint4 u4; unsigned short s[8]; } v0, v1;
      v0.u4 = *(const uint4*)(VB + kh * 72 + quad * 16);
      v1.u4 = *(const uint4*)(VB + kh * 72 + quad * 16 + 8);
#pragma unroll
      for (int dd = 0; dd < 8; ++dd) {
        o[dd]     += a * bf2f(v0.s[dd]);
        o[dd + 8] += a * bf2f(v1.s[dd]);
      }
    }
    const size_t rr = (size_t)bA[tk] * TT + (size_t)lm * 512 + (t >> 4);
    unsigned short* yp = Y + rr * 1024 + (t & 15) * 64 + quad * 16;
    union { uint4 u4; unsigned short s[8]; } o1, o2;
#pragma unroll
    for (int dd = 0; dd < 8; ++dd) o1.s[dd] = f2bf(o[dd]);
#pragma unroll
    for (int dd = 0; dd < 8; ++dd) o2.s[dd] = f2bf(o[8 + dd]);
    ((uint4*)yp)[0] = o1.u4;
    ((uint4*)yp)[1] = o2.u4;
#endif
  }
}

// ---------------------------------------------------------------------------
extern "C" void kernel_launch(void* const* d_in, const int* in_sizes, int n_in,
                              void* d_out, int out_size, void* d_ws, size_t ws_size,
                              hipStream_t stream) {
  const float* x    = (const float*)d_in[0];  // (2,8192,1024) fp32
  const float* Wqkv = (const float*)d_in[1];  // (3072,1024)  fp32
  const float* Wout = (const float*)d_in[2];  // (1024,1024)  fp32
  float* out = (float*)d_out;                 // (2,8192,1024) fp32

  // ws (56 MiB, proven): Y 32 | Wqkvb 6 | Woutb 2 | xb 16
  // d_out (67.1 MB): qkv chunk 50.3 MB at 0, rope table 2 MiB at +52 MiB.
  unsigned short* Y     = (unsigned short*)d_ws;
  unsigned short* Wqkvb = Y + (size_t)BT * 1024;
  unsigned short* Woutb = Wqkvb + (size_t)3072 * 1024;
  unsigned short* xb    = Woutb + (size_t)1024 * 1024;
  unsigned short* qkvC  = (unsigned short*)d_out;
  float2* tab           = (float2*)((char*)d_out + (size_t)52 * 1024 * 1024);

  // merged prep: rope table (1024 blocks) + Wqkv cvt (3072) + Wout cvt (1024)
  prep_k<<<dim3(5120), dim3(256), 0, stream>>>(Wqkv, Wout, Wqkvb, Woutb, tab);

  for (int base = 0; base < BT; base += MCH) {
    cvt_f2b<<<dim3(MCH * 1024 / 4 / 256), dim3(256), 0, stream>>>(
        x + (size_t)base * 1024, xb, MCH * 1024 / 4);
    gemm_k32<false><<<dim3((MCH / 256) * (3072 / 128)), dim3(512), 0, stream>>>(
        xb, Wqkvb, qkvC, MCH, 3072, 1024);
    attn_rope_k<<<dim3(MCH / 8), dim3(256), 0, stream>>>(qkvC, tab, Y, base);
  }

  // out = Y @ Wout^T : M=16384, N=1024, K=1024 (fp32 output)
  gemm_k32<true><<<dim3((BT / 256) * (1024 / 128)), dim3(512), 0, stream>>>(
      Y, Woutb, out, BT, 1024, 1024);
}

// Round 8
// 311.967 us; speedup vs baseline: 1.0016x; 1.0016x over previous
//
#include <hip/hip_runtime.h>
#include <stdint.h>

#define TT 8192          // sequence length T
#define BT 16384         // B*T tokens
#define MCH 8192         // token chunk for qkv GEMM + attention

typedef __attribute__((ext_vector_type(8))) __bf16 bf16x8;
typedef __attribute__((ext_vector_type(4))) __bf16 bf16x4;
typedef __attribute__((ext_vector_type(4))) short short4v;
typedef __attribute__((ext_vector_type(4))) float floatx4;

__device__ __forceinline__ float bf2f(unsigned short h) {
  union { unsigned u; float f; } x; x.u = ((unsigned)h) << 16; return x.f;
}
__device__ __forceinline__ unsigned short f2bf(float f) {
  union { float f; unsigned u; } x; x.f = f;
  unsigned r = (x.u + 0x7fffu + ((x.u >> 16) & 1u)) >> 16;
  return (unsigned short)r;
}
__device__ __forceinline__ void async16(const void* g, void* l) {
  __builtin_amdgcn_global_load_lds(
      (__attribute__((address_space(1))) void*)g,
      (__attribute__((address_space(3))) void*)l, 16, 0, 0);
}

// ---------------------------------------------------------------------------
// fp32 -> bf16 conversion (round-to-nearest-even), float4 vectorized.
// ---------------------------------------------------------------------------
__global__ __launch_bounds__(256) void cvt_f2b(
    const float* __restrict__ src, unsigned short* __restrict__ dst, int n4) {
  const int i = blockIdx.x * 256 + threadIdx.x;
  if (i < n4) {
    const float4 f = ((const float4*)src)[i];
    union { uint2 u2; unsigned short s[4]; } o;
    o.s[0] = f2bf(f.x); o.s[1] = f2bf(f.y);
    o.s[2] = f2bf(f.z); o.s[3] = f2bf(f.w);
    ((uint2*)dst)[i] = o.u2;
  }
}

// ---------------------------------------------------------------------------
// Merged prep: RoPE table + Wqkv cvt + Wout cvt in one dispatch.
// blocks [0,1024): tab[t*32+p] = (cos,sin) of t * 10000^(-p/32)
// blocks [1024,4096): Wqkv fp32->bf16 (786432 float4s)
// blocks [4096,5120): Wout fp32->bf16 (262144 float4s)
// ---------------------------------------------------------------------------
__global__ __launch_bounds__(256) void prep_k(
    const float* __restrict__ Wqkv, const float* __restrict__ Wout,
    unsigned short* __restrict__ Wqkvb, unsigned short* __restrict__ Woutb,
    float2* __restrict__ tab) {
  const int bx = blockIdx.x;
  const int tid = threadIdx.x;
  if (bx < 1024) {
    const int i = bx * 256 + tid;
    const int t = i >> 5, p = i & 31;
    const float f = (float)t * exp2f((float)p * -0.41524101186092f); // -log2(1e4)/32
    float s, c;
    sincosf(f, &s, &c);
    tab[i] = make_float2(c, s);
  } else {
    const float* src;
    unsigned short* dst;
    int i;
    if (bx < 4096) { src = Wqkv; dst = Wqkvb; i = (bx - 1024) * 256 + tid; }
    else           { src = Wout; dst = Woutb; i = (bx - 4096) * 256 + tid; }
    const float4 f = ((const float4*)src)[i];
    union { uint2 u2; unsigned short s[4]; } o;
    o.s[0] = f2bf(f.x); o.s[1] = f2bf(f.y);
    o.s[2] = f2bf(f.z); o.s[3] = f2bf(f.w);
    ((uint2*)dst)[i] = o.u2;
  }
}

// ---------------------------------------------------------------------------
// GEMM, occupancy-first pipelined schedule (round-2 exact — best measured):
// C[M,N] = A[M,K] . W[N,K]^T
// BM=256, BN=128, BK=32, 8 waves (4M x 2N), wave-tile 64x64 (acc[4][4]),
// LDS 48 KiB double-buffered, __launch_bounds__(512,4) capping regs so
// 2 blocks/CU (16 waves) fit. One phase per K-tile:
// {8x ds_read_b128 -> barrier -> lgkmcnt(0) -> stage(t+2, 3x gload_lds)
//  -> setprio(1) 16x MFMA setprio(0) -> vmcnt(3) -> barrier}.
// Counted vmcnt(3) keeps the next tile's loads in flight across barriers.
// XOR swizzle chunk ^= (row>>1)&3 on both stage-source and ds_read addr
// (measured 0 bank conflicts). XCD-aware blockIdx swizzle.
// Requires: M%256==0, N%128==0, K%32==0, K/32>=2, grid%8==0.
// ---------------------------------------------------------------------------
template <bool CF32>
__global__ __launch_bounds__(512, 4) void gemm_k32(
    const unsigned short* __restrict__ A,
    const unsigned short* __restrict__ W,
    void* __restrict__ C,
    int M, int N, int K)
{
  // per buf: A [256][32] (16 KB) + B [128][32] (8 KB) = 24 KB; x2 = 48 KiB
  __shared__ __align__(16) unsigned short sm[2][(256 + 128) * 32];

  const int tid  = threadIdx.x;
  const int lane = tid & 63;
  const int wid  = tid >> 6;
  const int wr   = wid >> 1;          // 0..3 : wave row (M, 64 rows each)
  const int wc   = wid & 1;           // 0..1 : wave col (N, 64 cols each)
  const int lm   = lane & 15;
  const int kg   = lane >> 4;
  const int cxor = (lm >> 1) & 3;     // read-side swizzle term ((row>>1)&3)

  // XCD-aware swizzle (grid % 8 == 0 for both call sites -> bijective)
  const int nb  = N >> 7;
  const int cpx = (int)gridDim.x >> 3;
  const int bid = blockIdx.x;
  const int swz = (bid & 7) * cpx + (bid >> 3);
  const int bm  = swz / nb;
  const int bn  = swz % nb;

  const int NT = K >> 5;              // K-tiles of 32

  // ---- staging geometry: 3 x global_load_lds(16B) per wave per tile ----
  const int sr  = lane >> 2;
  const int scb = lane & 3;
  const unsigned short* gsrc0;
  const unsigned short* gsrc1;
  const unsigned short* gsrc2;
  {
    const int r0 = wid * 16 + sr;          // 0..127
    const int r1 = 128 + r0;               // 128..255
    const int rB = wid * 16 + sr;          // 0..127
    gsrc0 = A + (size_t)(bm * 256 + r0) * (size_t)K + ((scb ^ ((r0 >> 1) & 3)) << 3);
    gsrc1 = A + (size_t)(bm * 256 + r1) * (size_t)K + ((scb ^ ((r1 >> 1) & 3)) << 3);
    gsrc2 = W + (size_t)(bn * 128 + rB) * (size_t)K + ((scb ^ ((rB >> 1) & 3)) << 3);
  }
  const int ld0 = wid * 1024;              // A half 0
  const int ld1 = 8192 + wid * 1024;       // A half 1
  const int ld2 = 16384 + wid * 1024;      // B

  auto stage_tile = [&](int tt) {
    char* lb = (char*)sm[tt & 1];
    const size_t koff = (size_t)tt << 5;   // element offset along K
    async16(gsrc0 + koff, lb + ld0);
    async16(gsrc1 + koff, lb + ld1);
    async16(gsrc2 + koff, lb + ld2);
  };

  floatx4 acc[4][4];
  floatx4 z = {0.f, 0.f, 0.f, 0.f};
#pragma unroll
  for (int i = 0; i < 4; ++i)
#pragma unroll
    for (int j = 0; j < 4; ++j) acc[i][j] = z;

  // ---- prologue: tiles 0 and 1 in flight; gate on tile-0 residency ----
  stage_tile(0);
  stage_tile(1);
  asm volatile("s_waitcnt vmcnt(3)" ::: "memory");
  __builtin_amdgcn_s_barrier();
  __builtin_amdgcn_sched_barrier(0);

  for (int t = 0; t < NT; ++t) {
    const unsigned short* Ab = sm[t & 1];
    const unsigned short* Bb = Ab + 256 * 32;

    bf16x8 af[4], bfr[4];
#pragma unroll
    for (int i = 0; i < 4; ++i) {
      const int rr = wr * 64 + i * 16 + lm;
      af[i] = *(const bf16x8*)(Ab + rr * 32 + ((kg ^ cxor) << 3));
    }
#pragma unroll
    for (int j = 0; j < 4; ++j) {
      const int rr = wc * 64 + j * 16 + lm;
      bfr[j] = *(const bf16x8*)(Bb + rr * 32 + ((kg ^ cxor) << 3));
    }

    // all waves' reads of this tile issued before anyone overwrites the buf
    __builtin_amdgcn_s_barrier();
    asm volatile("s_waitcnt lgkmcnt(0)" ::: "memory");
    __builtin_amdgcn_sched_barrier(0);

    if (t + 2 < NT) stage_tile(t + 2);   // overwrites buf just consumed

    __builtin_amdgcn_s_setprio(1);
#pragma unroll
    for (int i = 0; i < 4; ++i)
#pragma unroll
      for (int j = 0; j < 4; ++j)
        acc[i][j] = __builtin_amdgcn_mfma_f32_16x16x32_bf16(
            af[i], bfr[j], acc[i][j], 0, 0, 0);
    __builtin_amdgcn_s_setprio(0);

    if (t + 1 < NT) {
      // gate: tile t+1 resident; tile t+2's 3 loads may stay in flight.
      if (t + 2 < NT)
        asm volatile("s_waitcnt vmcnt(3)" ::: "memory");
      else
        asm volatile("s_waitcnt vmcnt(0)" ::: "memory");
      __builtin_amdgcn_s_barrier();
      __builtin_amdgcn_sched_barrier(0);
    }
  }

  // ---- epilogue ----
#pragma unroll
  for (int i = 0; i < 4; ++i) {
    const int row0 = bm * 256 + wr * 64 + i * 16 + kg * 4;
#pragma unroll
    for (int j = 0; j < 4; ++j) {
      const int col = bn * 128 + wc * 64 + j * 16 + lm;
#pragma unroll
      for (int r = 0; r < 4; ++r) {
        if (CF32)
          ((float*)C)[(size_t)(row0 + r) * N + col] = acc[i][j][r];
        else
          ((unsigned short*)C)[(size_t)(row0 + r) * N + col] = f2bf(acc[i][j][r]);
      }
    }
  }
}

// ---------------------------------------------------------------------------
// MFMA-based per-token head-attention with fused RoPE (table-based).
// One token per wave, 4 waves / 256-thr block. Q/K never touch LDS:
// in-register RoPE + ds_bpermute lane permutation builds the MFMA fragments
// (dst lane (lm,quad), half h takes source lane (lm&7)*8+h*4+quad's 16B
// chunk; chunk 0/1 = Q, 2/3 = K, selected by lm<8). V staged per-wave in
// LDS [16][72]. Scores S^T = K.Q^T -> s4[r] = S[lm][quad*4+r]; PV via
// mfma_16x16x16 (S^T C-layout == P A-layout).
// STORE FIX (this round): instead of 16 x 2B scattered global stores per
// lane (4x32B fragments at 1MB stride per instruction — HBM write-efficiency
// collapse), each wave drops O into sO[tok][qh*64+d] (LDS), then after
// __syncthreads the block writes 16 qh-segments x 512B contiguous
// (4 tokens share t>>4 and b), as 512 b128 stores — fully coalesced.
// Output layout (== reference transpose(0,2,1,3).reshape):
//   Y[b*8192 + qh*512 + t/16][(t&15)*64 + d]
// ---------------------------------------------------------------------------
#if defined(__has_builtin)
#if __has_builtin(__builtin_amdgcn_mfma_f32_16x16x16_bf16)
#define PV_MFMA 1
#define PV_MFMA_CALL(a, b, c) __builtin_amdgcn_mfma_f32_16x16x16_bf16( \
    *(bf16x4*)&(a), *(bf16x4*)&(b), (c), 0, 0, 0)
#elif __has_builtin(__builtin_amdgcn_mfma_f32_16x16x16bf16_1k)
#define PV_MFMA 1
#define PV_MFMA_CALL(a, b, c) __builtin_amdgcn_mfma_f32_16x16x16bf16_1k( \
    (a), (b), (c), 0, 0, 0)
#else
#define PV_MFMA 0
#endif
#else
#define PV_MFMA 0
#endif

__global__ __launch_bounds__(256, 4) void attn_rope_k(
    const unsigned short* __restrict__ qkv,   // chunk-local, MCH tokens
    const float2* __restrict__ tab,
    unsigned short* __restrict__ Y,
    int base)
{
  // per-wave V slot [16 heads][72] + per-block O transpose stage [4][1024]
  __shared__ __align__(16) unsigned short sV[4][16 * 72];
  __shared__ __align__(16) unsigned short sO[4][1024];
#if !PV_MFMA
  __shared__ float sP[4][256];
#endif

  const int wave = threadIdx.x >> 6;
  const int lane = threadIdx.x & 63;
  const int lm   = lane & 15;
  const int quad = lane >> 4;
  const int ml   = blockIdx.x * 4 + wave;   // chunk-local token
  const int m    = base + ml;
  const int t    = m & (TT - 1);
  unsigned short* VB = sV[wave];

  const int hlo = lane >> 3;          // head index for even chunks (odd: +8)
  const int d0  = (lane & 7) * 8;     // dim offset of this lane's chunk
  const int p0  = d0 >> 1;            // rope table offset

  // ---- issue loads (6 qkv b128 + 2 tab f4) ----
  uint4 R[6];
  const uint4* row = (const uint4*)(qkv + (size_t)ml * 3072);
#pragma unroll
  for (int i = 0; i < 6; ++i) R[i] = row[lane + 64 * i];
  const float4 CS0 = *(const float4*)(tab + (t << 5) + p0);
  const float4 CS1 = *(const float4*)(tab + (t << 5) + p0 + 2);
  const float cs[4] = {CS0.x, CS0.z, CS1.x, CS1.z};
  const float sn[4] = {CS0.y, CS0.w, CS1.y, CS1.w};

  // ---- RoPE in-register on the 4 Q/K chunks ----
  uint4 P[4];
#pragma unroll
  for (int i = 0; i < 4; ++i) {
    union { uint4 u4; unsigned short s[8]; } cv;
    cv.u4 = R[i];
    float f[8];
#pragma unroll
    for (int j = 0; j < 8; ++j) f[j] = bf2f(cv.s[j]);
#pragma unroll
    for (int j = 0; j < 4; ++j) {
      const float x1 = f[2 * j], x2 = f[2 * j + 1];
      cv.s[2 * j]     = f2bf(x1 * cs[j] - x2 * sn[j]);
      cv.s[2 * j + 1] = f2bf(x2 * cs[j] + x1 * sn[j]);
    }
    P[i] = cv.u4;
  }

  // ---- V -> LDS (2 b128 writes; no rope) ----
  *(uint4*)(VB + hlo * 72 + d0)       = R[4];
  *(uint4*)(VB + (8 + hlo) * 72 + d0) = R[5];

  // ---- scores: S^T = K.Q^T; fragments via ds_bpermute lane permute ----
  __builtin_amdgcn_s_setprio(1);
  floatx4 accS = {0.f, 0.f, 0.f, 0.f};
#pragma unroll
  for (int half = 0; half < 2; ++half) {
    const int bpi = (((lm & 7) * 8) + half * 4 + quad) * 4;
    union { int w[4]; bf16x8 v; } kf, qf;
#pragma unroll
    for (int w = 0; w < 4; ++w) {
      const int q0 = __builtin_amdgcn_ds_bpermute(bpi, (int)(&P[0].x)[w]);
      const int q1 = __builtin_amdgcn_ds_bpermute(bpi, (int)(&P[1].x)[w]);
      qf.w[w] = lm < 8 ? q0 : q1;
      const int k0 = __builtin_amdgcn_ds_bpermute(bpi, (int)(&P[2].x)[w]);
      const int k1 = __builtin_amdgcn_ds_bpermute(bpi, (int)(&P[3].x)[w]);
      kf.w[w] = lm < 8 ? k0 : k1;
    }
    accS = __builtin_amdgcn_mfma_f32_16x16x32_bf16(kf.v, qf.v, accS, 0, 0, 0);
  }

  // accS[r] = S[q=lm][k=quad*4+r] ; softmax over the 16 head-keys
  float s4[4];
  float mx = -1e30f;
#pragma unroll
  for (int j = 0; j < 4; ++j) { s4[j] = accS[j] * 0.125f; mx = fmaxf(mx, s4[j]); }
  mx = fmaxf(mx, __shfl_xor(mx, 16, 64));
  mx = fmaxf(mx, __shfl_xor(mx, 32, 64));
  float sum = 0.f;
#pragma unroll
  for (int j = 0; j < 4; ++j) { s4[j] = __expf(s4[j] - mx); sum += s4[j]; }
  sum += __shfl_xor(sum, 16, 64);
  sum += __shfl_xor(sum, 32, 64);
  const float inv = 1.0f / sum;

#if PV_MFMA
  // ---- PV via mfma_16x16x16 (S^T C-layout == P A-layout) ----
  union { short4v v; unsigned short s[4]; } pf;
#pragma unroll
  for (int j = 0; j < 4; ++j) pf.s[j] = f2bf(s4[j] * inv);
  // hoist ALL 16 V reads (independent) ahead of the 4 MFMAs
  unsigned short vs[16];
#pragma unroll
  for (int dtile = 0; dtile < 4; ++dtile)
#pragma unroll
    for (int j = 0; j < 4; ++j)
      vs[dtile * 4 + j] = VB[(quad * 4 + j) * 72 + dtile * 16 + lm];
#pragma unroll
  for (int dtile = 0; dtile < 4; ++dtile) {
    union { short4v v; unsigned short s[4]; } vf;
#pragma unroll
    for (int j = 0; j < 4; ++j) vf.s[j] = vs[dtile * 4 + j];
    floatx4 accO = {0.f, 0.f, 0.f, 0.f};
    accO = PV_MFMA_CALL(pf.v, vf.v, accO);
    // O[qh=quad*4+r][d=dtile*16+lm] -> LDS transpose stage
#pragma unroll
    for (int r = 0; r < 4; ++r)
      sO[wave][(quad * 4 + r) * 64 + dtile * 16 + lm] = f2bf(accO[r]);
  }
  __builtin_amdgcn_s_setprio(0);
#else
  // ---- VALU fallback: P via per-wave LDS slice (wave-local drains) ----
  __builtin_amdgcn_s_setprio(0);
  float* Pp = sP[wave];
#pragma unroll
  for (int j = 0; j < 4; ++j) Pp[(quad * 4 + j) * 16 + lm] = s4[j] * inv;
  asm volatile("s_waitcnt lgkmcnt(0)" ::: "memory");
  __builtin_amdgcn_sched_barrier(0);
  float o[16];
#pragma unroll
  for (int dd = 0; dd < 16; ++dd) o[dd] = 0.f;
#pragma unroll
  for (int kh = 0; kh < 16; ++kh) {
    const float a = Pp[kh * 16 + lm];
    union { uint4 u4; unsigned short s[8]; } v0, v1;
    v0.u4 = *(const uint4*)(VB + kh * 72 + quad * 16);
    v1.u4 = *(const uint4*)(VB + kh * 72 + quad * 16 + 8);
#pragma unroll
    for (int dd = 0; dd < 8; ++dd) {
      o[dd]     += a * bf2f(v0.s[dd]);
      o[dd + 8] += a * bf2f(v1.s[dd]);
    }
  }
  // o[dd] = O[qh=lm][d=quad*16+dd] -> LDS transpose stage
#pragma unroll
  for (int dd = 0; dd < 16; ++dd)
    sO[wave][lm * 64 + quad * 16 + dd] = f2bf(o[dd]);
#endif

  // ---- coalesced Y store: 16 qh-segments x 512B contiguous per block ----
  __syncthreads();
  const int m0 = base + blockIdx.x * 4;     // block's first token
  const int t0 = m0 & (TT - 1);
  const int b0 = m0 >> 13;
#pragma unroll
  for (int s = 0; s < 2; ++s) {
    const int u   = threadIdx.x + s * 256;  // 0..511
    const int qh  = u >> 5;
    const int rem = u & 31;                 // tk*8 + e8
    const int tk  = rem >> 3;
    const int e8  = (rem & 7) * 8;
    const uint4 v = *(const uint4*)(&sO[tk][qh * 64 + e8]);
    const size_t off = (((size_t)(b0 * TT + qh * 512 + (t0 >> 4))) << 10)
                       + (t0 & 15) * 64 + rem * 8;
    *(uint4*)(Y + off) = v;
  }
}

// ---------------------------------------------------------------------------
extern "C" void kernel_launch(void* const* d_in, const int* in_sizes, int n_in,
                              void* d_out, int out_size, void* d_ws, size_t ws_size,
                              hipStream_t stream) {
  const float* x    = (const float*)d_in[0];  // (2,8192,1024) fp32
  const float* Wqkv = (const float*)d_in[1];  // (3072,1024)  fp32
  const float* Wout = (const float*)d_in[2];  // (1024,1024)  fp32
  float* out = (float*)d_out;                 // (2,8192,1024) fp32

  // ws (56 MiB, proven): Y 32 | Wqkvb 6 | Woutb 2 | xb 16
  // d_out (67.1 MB): qkv chunk 50.3 MB at 0, rope table 2 MiB at +52 MiB.
  unsigned short* Y     = (unsigned short*)d_ws;
  unsigned short* Wqkvb = Y + (size_t)BT * 1024;
  unsigned short* Woutb = Wqkvb + (size_t)3072 * 1024;
  unsigned short* xb    = Woutb + (size_t)1024 * 1024;
  unsigned short* qkvC  = (unsigned short*)d_out;
  float2* tab           = (float2*)((char*)d_out + (size_t)52 * 1024 * 1024);

  // merged prep: rope table (1024 blocks) + Wqkv cvt (3072) + Wout cvt (1024)
  prep_k<<<dim3(5120), dim3(256), 0, stream>>>(Wqkv, Wout, Wqkvb, Woutb, tab);

  for (int base = 0; base < BT; base += MCH) {
    cvt_f2b<<<dim3(MCH * 1024 / 4 / 256), dim3(256), 0, stream>>>(
        x + (size_t)base * 1024, xb, MCH * 1024 / 4);
    gemm_k32<false><<<dim3((MCH / 256) * (3072 / 128)), dim3(512), 0, stream>>>(
        xb, Wqkvb, qkvC, MCH, 3072, 1024);
    attn_rope_k<<<dim3(MCH / 4), dim3(256), 0, stream>>>(qkvC, tab, Y, base);
  }

  // out = Y @ Wout^T : M=16384, N=1024, K=1024 (fp32 output)
  gemm_k32<true><<<dim3((BT / 256) * (1024 / 128)), dim3(512), 0, stream>>>(
      Y, Woutb, out, BT, 1024, 1024);
}